// Round 5
// baseline (143.475 us; speedup 1.0000x reference)
//
#include <hip/hip_runtime.h>

// FlexAttention (sliding-window causal + per-head sink), R14.
// B=2,H=16,S=2048,D=64,W=1024.
//
// R14 = R13 + T15 two-tile rounds. Evidence R9/R11/R13: main time ==
// 27 wave-tiles/SIMD x ~3900cy serial chain, insensitive to memory traffic
// (FETCH 125->43MB: -3us) and wave count (3 vs 4 waves/SIMD identical).
// So: cut the chain count. Each barrier round now computes TWO consecutive
// K-tiles: QK(a)+QK(b) = 4 independent MFMA chains (pipe fills), ONE joint
// online-softmax over the 128-key block (identical math to two sequential
// steps; one shfl-reduce/defer-check/rescale instead of two; 8-chain tree
// sum), exchange(b) VALU covers PV(a) MFMA stalls. Rounds/bin: 9 -> 5
// (verified for all 24 bins with per-segment pairing).
//  - LDS 64KB: 2x2 buffers (pair-dbuf) -> 2 blocks/CU (law says free).
//  - __launch_bounds__(256,2): reg cap 256, peak live ~210, no spill.
//  - Keeps R13 grafts: XCD-pinned decode, defer-max, tree-max, setprio.
// Layouts (m74/m101): A[m=l&31][k=(l>>5)*8+j], B[k=..][n=l&31],
// C/D[row=(rg&3)+8*(rg>>2)+4*(l>>5)][col=l&31].

typedef __bf16 bf16x8 __attribute__((ext_vector_type(8)));
typedef __bf16 bf16x4 __attribute__((ext_vector_type(4)));
typedef float  f32x16 __attribute__((ext_vector_type(16)));

#define NT 256
#define NEG_BIG (-3.0e38f)

__device__ __forceinline__ int swz(int row, int gran) {
    return row * 64 + ((gran ^ ((row >> 1) & 7)) << 3);
}

__device__ __forceinline__ bf16x4 xswap32(bf16x4 v) {
    union { bf16x4 v; int i[2]; } u;
    u.v = v;
    u.i[0] = __shfl_xor(u.i[0], 32, 64);
    u.i[1] = __shfl_xor(u.i[1], 32, 64);
    return u.v;
}

// ---- baked schedule (R5/R6, verified): 24 bins/bh x exactly 9 tiles ----
__device__ const int SEG_N[24] = {3,2,2,2,2,1,2,1, 1,1,1,1,1,1,1,1, 1,1,1,1,1,1,1,1};
__device__ const int SEG_IT[24][3] = {
  {0,1,2},{2,3,0},{3,4,0},{4,5,0},{5,6,0},{6,0,0},{6,7,0},{7,0,0},
  {8,0,0},{8,0,0},{9,0,0},{9,0,0},{10,0,0},{10,0,0},{11,0,0},{11,0,0},
  {12,0,0},{12,0,0},{13,0,0},{13,0,0},{14,0,0},{14,0,0},{15,0,0},{15,0,0}};
__device__ const int SEG_J0[24][3] = {
  {0,0,0},{3,0,0},{6,0,0},{7,0,0},{6,0,0},{3,0,0},{12,0,0},{7,0,0},
  {0,0,0},{9,0,0},{0,0,0},{9,0,0},{0,0,0},{9,0,0},{0,0,0},{9,0,0},
  {0,0,0},{9,0,0},{0,0,0},{9,0,0},{0,0,0},{9,0,0},{0,0,0},{9,0,0}};
__device__ const int SEG_J1[24][3] = {
  {2,4,3},{6,6,0},{8,7,0},{10,6,0},{12,3,0},{12,0,0},{14,7,0},{16,0,0},
  {9,0,0},{18,0,0},{9,0,0},{18,0,0},{9,0,0},{18,0,0},{9,0,0},{18,0,0},
  {9,0,0},{18,0,0},{9,0,0},{18,0,0},{9,0,0},{18,0,0},{9,0,0},{18,0,0}};
__device__ const int SEG_SX[24][3] = {
  {0,0,0},{1,0,0},{1,0,0},{1,0,0},{1,0,0},{1,0,0},{2,0,0},{1,0,0},
  {0,0,0},{1,0,0},{0,0,0},{1,0,0},{0,0,0},{1,0,0},{0,0,0},{1,0,0},
  {0,0,0},{1,0,0},{0,0,0},{1,0,0},{0,0,0},{1,0,0},{0,0,0},{1,0,0}};
__device__ const int NSEG_ITEM[16] = {1,1,2,2,2,2,3,2, 2,2,2,2,2,2,2,2};

// ---- per-tile building blocks (R13-proven bodies) ----
__device__ __forceinline__ void qk_mfma(const __bf16* kb, const bf16x8 bq[4],
                                        int c, int hl, f32x16& s0, f32x16& s1) {
    #pragma unroll
    for (int ks = 0; ks < 4; ++ks) {
        bf16x8 ka0 = *(const bf16x8*)&kb[swz(c,      2 * ks + hl)];
        bf16x8 ka1 = *(const bf16x8*)&kb[swz(32 + c, 2 * ks + hl)];
        s0 = __builtin_amdgcn_mfma_f32_32x32x16_bf16(ka0, bq[ks], s0, 0, 0, 0);
        s1 = __builtin_amdgcn_mfma_f32_32x32x16_bf16(ka1, bq[ks], s1, 0, 0, 0);
    }
}

__device__ __forceinline__ void pv_mfma(const __bf16* vb, const bf16x8 bp[4],
                                        int c, int hl, f32x16& o0, f32x16& o1) {
    #pragma unroll
    for (int ks = 0; ks < 4; ++ks) {
        bf16x8 va0 = *(const bf16x8*)&vb[swz(c,      2 * ks + hl)];
        bf16x8 va1 = *(const bf16x8*)&vb[swz(32 + c, 2 * ks + hl)];
        o0 = __builtin_amdgcn_mfma_f32_32x32x16_bf16(va0, bp[ks], o0, 0, 0, 0);
        o1 = __builtin_amdgcn_mfma_f32_32x32x16_bf16(va1, bp[ks], o1, 0, 0, 0);
    }
}

__device__ __forceinline__ void mask_tile(f32x16& s0, f32x16& s1,
                                          int k0, int qi, int W, int hl) {
    #pragma unroll
    for (int rg = 0; rg < 16; ++rg) {
        const int kb2 = (rg & 3) + 8 * (rg >> 2) + 4 * hl;
        const int ki0 = k0 + kb2, ki1 = k0 + 32 + kb2;
        if (!((ki0 <= qi) && (qi - ki0 <= W))) s0[rg] = -1e30f;
        if (!((ki1 <= qi) && (qi - ki1 <= W))) s1[rg] = -1e30f;
    }
}

__device__ __forceinline__ void exch_bp(const f32x16 s0, const f32x16 s1,
                                        int hl, bf16x8 bp[4]) {
    bf16x4 qA = { (__bf16)s0[0],  (__bf16)s0[1],  (__bf16)s0[2],  (__bf16)s0[3]  };
    bf16x4 qB = { (__bf16)s0[4],  (__bf16)s0[5],  (__bf16)s0[6],  (__bf16)s0[7]  };
    bf16x4 qC = { (__bf16)s0[8],  (__bf16)s0[9],  (__bf16)s0[10], (__bf16)s0[11] };
    bf16x4 qD = { (__bf16)s0[12], (__bf16)s0[13], (__bf16)s0[14], (__bf16)s0[15] };
    bf16x4 qE = { (__bf16)s1[0],  (__bf16)s1[1],  (__bf16)s1[2],  (__bf16)s1[3]  };
    bf16x4 qF = { (__bf16)s1[4],  (__bf16)s1[5],  (__bf16)s1[6],  (__bf16)s1[7]  };
    bf16x4 qG = { (__bf16)s1[8],  (__bf16)s1[9],  (__bf16)s1[10], (__bf16)s1[11] };
    bf16x4 qH = { (__bf16)s1[12], (__bf16)s1[13], (__bf16)s1[14], (__bf16)s1[15] };
    bf16x4 r0 = xswap32(hl ? qA : qB);
    bf16x4 r1 = xswap32(hl ? qC : qD);
    bf16x4 r2 = xswap32(hl ? qE : qF);
    bf16x4 r3 = xswap32(hl ? qG : qH);
    bf16x4 lo0 = hl ? r0 : qA, hi0 = hl ? qB : r0;
    bf16x4 lo1 = hl ? r1 : qC, hi1 = hl ? qD : r1;
    bf16x4 lo2 = hl ? r2 : qE, hi2 = hl ? qF : r2;
    bf16x4 lo3 = hl ? r3 : qG, hi3 = hl ? qH : r3;
    #pragma unroll
    for (int e = 0; e < 4; ++e) {
        bp[0][e] = lo0[e]; bp[0][4+e] = hi0[e];
        bp[1][e] = lo1[e]; bp[1][4+e] = hi1[e];
        bp[2][e] = lo2[e]; bp[2][4+e] = hi2[e];
        bp[3][e] = lo3[e]; bp[3][4+e] = hi3[e];
    }
}

__device__ __forceinline__ void stage_k(__bf16* dst, const float4* kr, int t) {
    #pragma unroll
    for (int i = 0; i < 4; ++i) {
        const int flat = i * NT + t;
        const int key = flat >> 4, dd = flat & 15;
        float4 f = kr[i];
        bf16x4 b = { (__bf16)f.x, (__bf16)f.y, (__bf16)f.z, (__bf16)f.w };
        *(bf16x4*)&dst[swz(key, dd >> 1) + (dd & 1) * 4] = b;
    }
}

__device__ __forceinline__ void stage_v(__bf16* dst, const float4* vr, int dgi, int kgi) {
    float4 a0 = vr[0], a1 = vr[1], a2 = vr[2], a3 = vr[3];
    bf16x4 w0 = { (__bf16)a0.x, (__bf16)a1.x, (__bf16)a2.x, (__bf16)a3.x };
    bf16x4 w1 = { (__bf16)a0.y, (__bf16)a1.y, (__bf16)a2.y, (__bf16)a3.y };
    bf16x4 w2 = { (__bf16)a0.z, (__bf16)a1.z, (__bf16)a2.z, (__bf16)a3.z };
    bf16x4 w3 = { (__bf16)a0.w, (__bf16)a1.w, (__bf16)a2.w, (__bf16)a3.w };
    const int gv = kgi >> 1, ov = (kgi & 1) * 4;
    *(bf16x4*)&dst[swz(4 * dgi + 0, gv) + ov] = w0;
    *(bf16x4*)&dst[swz(4 * dgi + 1, gv) + ov] = w1;
    *(bf16x4*)&dst[swz(4 * dgi + 2, gv) + ov] = w2;
    *(bf16x4*)&dst[swz(4 * dgi + 3, gv) + ov] = w3;
}

__global__ __launch_bounds__(NT, 2) void flex_r14_main(
    const float* __restrict__ Q, const float* __restrict__ K,
    const float* __restrict__ V, const float* __restrict__ SINKW,
    const int* __restrict__ SWIN, void* __restrict__ WS,
    float* __restrict__ OUT, const int H, const int S)
{
    const int t    = threadIdx.x;
    const int lane = t & 63;
    const int w    = t >> 6;
    const int c    = lane & 31;
    const int hl   = lane >> 5;
    const int W    = SWIN[0];
    const float scale = 0.125f;

    const int NBH = gridDim.x / 24;
    int bh, b24;
    if ((NBH & 7) == 0) {
        const int xcd  = blockIdx.x & 7;
        const int rest = blockIdx.x >> 3;
        const int G    = NBH >> 3;
        bh  = (rest % G) * 8 + xcd;
        b24 = rest / G;
    } else {
        bh  = blockIdx.x / 24;
        b24 = blockIdx.x - bh * 24;
    }
    const int h   = bh % H;
    const float sw = SINKW[h];

    // pair-double-buffered: [round-parity][tile-in-pair]
    __shared__ __align__(16) __bf16 k_lds[2][2][64 * 64];
    __shared__ __align__(16) __bf16 v_lds[2][2][64 * 64];

    const size_t basebh = (size_t)bh * S * 64;
    const float4* kp4 = (const float4*)(K + basebh);
    const float4* vp4 = (const float4*)(V + basebh);
    __bf16* O_ws  = (__bf16*)WS;
    float2* ml_ws = (float2*)((char*)WS + (size_t)NBH * 48 * 16384);

    const int dgi = t & 15;
    const int kgi = t >> 4;
    float4 kreg[8], vreg[8];

    const int ns = SEG_N[b24];

    // ---- prologue: load + stage first PAIR into parity 0 ----
    // (every bin's first segment has >= 2 tiles; verified for all 24 bins)
    {
        const int it0 = SEG_IT[b24][0];
        const int ktA0 = (2 * it0 - 16 > 0) ? (2 * it0 - 16) : 0;
        const int kt0 = ktA0 + SEG_J0[b24][0];
        #pragma unroll
        for (int i = 0; i < 4; ++i) {
            kreg[i]     = kp4[kt0 * 1024 + i * NT + t];
            kreg[4 + i] = kp4[(kt0 + 1) * 1024 + i * NT + t];
        }
        #pragma unroll
        for (int kk = 0; kk < 4; ++kk) {
            vreg[kk]     = vp4[kt0 * 1024 + (4 * kgi + kk) * 16 + dgi];
            vreg[4 + kk] = vp4[(kt0 + 1) * 1024 + (4 * kgi + kk) * 16 + dgi];
        }
        stage_k(&k_lds[0][0][0], &kreg[0], t);
        stage_v(&v_lds[0][0][0], &vreg[0], dgi, kgi);
        stage_k(&k_lds[0][1][0], &kreg[4], t);
        stage_v(&v_lds[0][1][0], &vreg[4], dgi, kgi);
    }

    int par = 0;

    for (int s = 0; s < ns; ++s) {
        const int item = SEG_IT[b24][s];
        const int j0   = SEG_J0[b24][s];
        const int j1   = SEG_J1[b24][s];
        const int sidx = SEG_SX[b24][s];
        const int ktA  = (2 * item - 16 > 0) ? (2 * item - 16) : 0;
        const int qw0  = item * 128 + 32 * w;
        const int qi   = qw0 + c;

        // ---- Q B-fragments (pre-scaled) ----
        bf16x8 bq[4];
        {
            const float4* qp4 = (const float4*)(Q + basebh + (size_t)qi * 64);
            #pragma unroll
            for (int ks = 0; ks < 4; ++ks) {
                float4 f0 = qp4[4 * ks + 2 * hl];
                float4 f1 = qp4[4 * ks + 2 * hl + 1];
                bq[ks][0] = (__bf16)(f0.x * scale); bq[ks][1] = (__bf16)(f0.y * scale);
                bq[ks][2] = (__bf16)(f0.z * scale); bq[ks][3] = (__bf16)(f0.w * scale);
                bq[ks][4] = (__bf16)(f1.x * scale); bq[ks][5] = (__bf16)(f1.y * scale);
                bq[ks][6] = (__bf16)(f1.z * scale); bq[ks][7] = (__bf16)(f1.w * scale);
            }
        }

        float mrun = (sidx == 0) ? sw : NEG_BIG;
        float lrun = (sidx == 0) ? 1.0f : 0.0f;
        f32x16 accO0, accO1;
        #pragma unroll
        for (int i = 0; i < 16; ++i) { accO0[i] = 0.0f; accO1[i] = 0.0f; }

        for (int j = j0; j < j1; j += 2) {
            const bool two = (j + 1 < j1);
            const int k0a = (ktA + j) * 64;
            const int k0b = k0a + 64;

            __syncthreads();   // buf[par] pair staged & visible; prev reads done

            // ---- prefetch next ROUND's pair ----
            int n0 = -1, n1 = -1;
            if (j + 2 < j1) {
                n0 = ktA + j + 2;
                if (j + 3 < j1) n1 = n0 + 1;
            } else if (s + 1 < ns) {
                const int it2  = SEG_IT[b24][s + 1];
                const int ktA2 = (2 * it2 - 16 > 0) ? (2 * it2 - 16) : 0;
                const int j02  = SEG_J0[b24][s + 1];
                n0 = ktA2 + j02;
                if (j02 + 1 < SEG_J1[b24][s + 1]) n1 = n0 + 1;
            }
            if (n0 >= 0) {
                #pragma unroll
                for (int i = 0; i < 4; ++i) kreg[i] = kp4[n0 * 1024 + i * NT + t];
                #pragma unroll
                for (int kk = 0; kk < 4; ++kk) vreg[kk] = vp4[n0 * 1024 + (4 * kgi + kk) * 16 + dgi];
            }
            if (n1 >= 0) {
                #pragma unroll
                for (int i = 0; i < 4; ++i) kreg[4 + i] = kp4[n1 * 1024 + i * NT + t];
                #pragma unroll
                for (int kk = 0; kk < 4; ++kk) vreg[4 + kk] = vp4[n1 * 1024 + (4 * kgi + kk) * 16 + dgi];
            }

            // ---- QK for both tiles (4 independent MFMA chains) ----
            f32x16 sa0, sa1, sb0, sb1;
            #pragma unroll
            for (int i = 0; i < 16; ++i) { sa0[i] = 0.0f; sa1[i] = 0.0f; sb0[i] = 0.0f; sb1[i] = 0.0f; }
            __builtin_amdgcn_s_setprio(1);
            qk_mfma(&k_lds[par][0][0], bq, c, hl, sa0, sa1);
            if (two) qk_mfma(&k_lds[par][1][0], bq, c, hl, sb0, sb1);
            __builtin_amdgcn_s_setprio(0);

            // ---- masks ----
            if (!((k0a + 63 <= qw0) && (qw0 + 31 - k0a <= W)))
                mask_tile(sa0, sa1, k0a, qi, W, hl);
            if (two && !((k0b + 63 <= qw0) && (qw0 + 31 - k0b <= W)))
                mask_tile(sb0, sb1, k0b, qi, W, hl);

            // ---- JOINT online softmax over the 128-key block ----
            float m8[8];
            #pragma unroll
            for (int i = 0; i < 4; ++i) {
                m8[i]   = fmaxf(fmaxf(sa0[4*i], sa0[4*i+1]), fmaxf(sa0[4*i+2], sa0[4*i+3]));
                m8[4+i] = fmaxf(fmaxf(sa1[4*i], sa1[4*i+1]), fmaxf(sa1[4*i+2], sa1[4*i+3]));
            }
            float mx = fmaxf(fmaxf(fmaxf(m8[0], m8[1]), fmaxf(m8[2], m8[3])),
                             fmaxf(fmaxf(m8[4], m8[5]), fmaxf(m8[6], m8[7])));
            if (two) {
                float n8[8];
                #pragma unroll
                for (int i = 0; i < 4; ++i) {
                    n8[i]   = fmaxf(fmaxf(sb0[4*i], sb0[4*i+1]), fmaxf(sb0[4*i+2], sb0[4*i+3]));
                    n8[4+i] = fmaxf(fmaxf(sb1[4*i], sb1[4*i+1]), fmaxf(sb1[4*i+2], sb1[4*i+3]));
                }
                mx = fmaxf(mx, fmaxf(fmaxf(fmaxf(n8[0], n8[1]), fmaxf(n8[2], n8[3])),
                                     fmaxf(fmaxf(n8[4], n8[5]), fmaxf(n8[6], n8[7]))));
            }
            mx = fmaxf(mx, __shfl_xor(mx, 32, 64));
            if (!__all(mx <= mrun + 8.0f)) {
                const float mnew  = fmaxf(mrun, mx);
                const float alpha = __expf(mrun - mnew);
                lrun *= alpha;
                #pragma unroll
                for (int i = 0; i < 16; ++i) { accO0[i] *= alpha; accO1[i] *= alpha; }
                mrun = mnew;
            }
            float sc[8];
            #pragma unroll
            for (int i = 0; i < 8; ++i) sc[i] = 0.0f;
            #pragma unroll
            for (int i = 0; i < 16; ++i) {
                float p0 = __expf(sa0[i] - mrun); sa0[i] = p0; sc[i & 3]       += p0;
                float p1 = __expf(sa1[i] - mrun); sa1[i] = p1; sc[4 + (i & 3)] += p1;
            }
            if (two) {
                #pragma unroll
                for (int i = 0; i < 16; ++i) {
                    float p0 = __expf(sb0[i] - mrun); sb0[i] = p0; sc[i & 3]       += p0;
                    float p1 = __expf(sb1[i] - mrun); sb1[i] = p1; sc[4 + (i & 3)] += p1;
                }
            }
            float ps = ((sc[0] + sc[1]) + (sc[2] + sc[3])) + ((sc[4] + sc[5]) + (sc[6] + sc[7]));
            ps += __shfl_xor(ps, 32, 64);
            lrun += ps;

            // ---- exchange + PV, tile a then tile b ----
            {
                bf16x8 bp[4];
                exch_bp(sa0, sa1, hl, bp);
                __builtin_amdgcn_s_setprio(1);
                pv_mfma(&v_lds[par][0][0], bp, c, hl, accO0, accO1);
                __builtin_amdgcn_s_setprio(0);
            }
            if (two) {
                bf16x8 bp[4];
                exch_bp(sb0, sb1, hl, bp);
                __builtin_amdgcn_s_setprio(1);
                pv_mfma(&v_lds[par][1][0], bp, c, hl, accO0, accO1);
                __builtin_amdgcn_s_setprio(0);
            }

            // ---- stage next round's pair into parity par^1 ----
            if (n0 >= 0) {
                stage_k(&k_lds[par ^ 1][0][0], &kreg[0], t);
                stage_v(&v_lds[par ^ 1][0][0], &vreg[0], dgi, kgi);
            }
            if (n1 >= 0) {
                stage_k(&k_lds[par ^ 1][1][0], &kreg[4], t);
                stage_v(&v_lds[par ^ 1][1][0], &vreg[4], dgi, kgi);
            }
            par ^= 1;
        }

        if (item < 2) {
            // ---- single-segment item: write normalized output directly ----
            const float inv = 1.0f / lrun;
            float* ob = OUT + basebh + (size_t)qi * 64;
            #pragma unroll
            for (int rg = 0; rg < 4; ++rg) {
                float4 f0 = { accO0[4*rg+0]*inv, accO0[4*rg+1]*inv,
                              accO0[4*rg+2]*inv, accO0[4*rg+3]*inv };
                float4 f1 = { accO1[4*rg+0]*inv, accO1[4*rg+1]*inv,
                              accO1[4*rg+2]*inv, accO1[4*rg+3]*inv };
                *(float4*)&ob[     8 * rg + 4 * hl] = f0;
                *(float4*)&ob[32 + 8 * rg + 4 * hl] = f1;
            }
        } else {
            // ---- write partials ----
            const int slot = (bh * 16 + item) * 3 + sidx;
            const int qrel = 32 * w + c;
            if (hl == 0) ml_ws[(size_t)slot * 128 + qrel] = make_float2(mrun, lrun);
            __bf16* Os = O_ws + (size_t)slot * 8192 + (size_t)qrel * 64;
            #pragma unroll
            for (int qd = 0; qd < 4; ++qd) {
                const int d0 = 8 * qd + 4 * hl;
                bf16x4 b0 = { (__bf16)accO0[4*qd+0], (__bf16)accO0[4*qd+1],
                              (__bf16)accO0[4*qd+2], (__bf16)accO0[4*qd+3] };
                bf16x4 b1 = { (__bf16)accO1[4*qd+0], (__bf16)accO1[4*qd+1],
                              (__bf16)accO1[4*qd+2], (__bf16)accO1[4*qd+3] };
                *(bf16x4*)&Os[d0]      = b0;
                *(bf16x4*)&Os[32 + d0] = b1;
            }
        }
    }
}

__global__ __launch_bounds__(256) void flex_r14_combine(
    const void* __restrict__ WS, float* __restrict__ OUT, const int H, const int S)
{
    const int NBH  = gridDim.x / 14;
    const int bi   = blockIdx.x;
    const int bh   = bi / 14;
    const int item = 2 + (bi - bh * 14);      // items 2..15 (multi-segment)
    const int ns   = NSEG_ITEM[item];
    const int t    = threadIdx.x;
    const int q    = t >> 1;
    const int half = t & 1;

    const __bf16* O_ws = (const __bf16*)WS;
    const float2* ml_ws = (const float2*)((const char*)WS + (size_t)NBH * 48 * 16384);
    const int base = (bh * 16 + item) * 3;

    float m[3], lv[3], a[3];
    float mst = NEG_BIG;
    for (int s = 0; s < ns; ++s) {
        float2 e = ml_ws[(size_t)(base + s) * 128 + q];
        m[s] = e.x; lv[s] = e.y;
        mst = fmaxf(mst, m[s]);
    }
    float lst = 0.0f;
    for (int s = 0; s < ns; ++s) { a[s] = __expf(m[s] - mst); lst += a[s] * lv[s]; }
    const float inv = 1.0f / lst;

    float acc[32];
    #pragma unroll
    for (int i = 0; i < 32; ++i) acc[i] = 0.0f;
    for (int s = 0; s < ns; ++s) {
        const __bf16* Os = O_ws + (size_t)(base + s) * 8192 + (size_t)q * 64 + 32 * half;
        const float as = a[s];
        #pragma unroll
        for (int v8 = 0; v8 < 4; ++v8) {
            bf16x8 o = *(const bf16x8*)&Os[8 * v8];
            #pragma unroll
            for (int jj = 0; jj < 8; ++jj) acc[8 * v8 + jj] += as * (float)o[jj];
        }
    }

    float* dst = OUT + (size_t)bh * S * 64 + (size_t)(item * 128 + q) * 64 + 32 * half;
    #pragma unroll
    for (int v4 = 0; v4 < 8; ++v4) {
        float4 f = { acc[4*v4+0] * inv, acc[4*v4+1] * inv,
                     acc[4*v4+2] * inv, acc[4*v4+3] * inv };
        *(float4*)&dst[4 * v4] = f;
    }
}

extern "C" void kernel_launch(void* const* d_in, const int* in_sizes, int n_in,
                              void* d_out, int out_size, void* d_ws, size_t ws_size,
                              hipStream_t stream) {
    const float* q     = (const float*)d_in[0];
    const float* k     = (const float*)d_in[1];
    const float* v     = (const float*)d_in[2];
    const float* sinkw = (const float*)d_in[3];
    const int*   swin  = (const int*)d_in[4];
    float* out = (float*)d_out;

    const int H = in_sizes[3];                   // 16
    const int S = 2048;
    const int B = in_sizes[0] / (H * S * 64);    // 2
    const int NBH = B * H;                       // 32

    flex_r14_main<<<dim3(NBH * 24), NT, 0, stream>>>(q, k, v, sinkw, swin, d_ws, out, H, S);
    flex_r14_combine<<<dim3(NBH * 14), 256, 0, stream>>>(d_ws, out, H, S);
}

// Round 7
// 130.208 us; speedup vs baseline: 1.1019x; 1.1019x over previous
//
#include <hip/hip_runtime.h>

// FlexAttention (sliding-window causal + per-head sink), R16.
// B=2,H=16,S=2048,D=64,W=1024.
//
// R16 = R15 with the register-aliasing hazard fixed. R15's failure root
// cause: xmax32/xsum32 initialized a=b=x; the compiler coalesced the two
// identical values into ONE VGPR, so v_permlane32_swap_b32 ran with
// vdst==vsrc (in-place half-swap, no reduce) -> wrong running max ->
// exp overflow (absmax 0.45, |out| up to 468). Fix: earlyclobber opaque
// v_mov ("=&v") forces a distinct register before the swap. The bf16x4
// exchange plswaps were never at risk (qA/qB hold distinct values).
// Verified semantics: permlane32_swap(a,b): a'={a.row0,b.row0},
// b'={a.row1,b.row1}  ==  R13's lo/hi exchange exactly.
// Keeps R13's: XCD-pinned decode, defer-max + tree-max, s_setprio around
// MFMA, 24-bin x 9-tile schedule (768 blocks = 3/CU), __launch_bounds__(256,3),
// in-kernel fp32->bf16 staging, LDS 32KB dbuf, one barrier/tile.
// Layouts (m74/m101): A[m=l&31][k=(l>>5)*8+j], B[k=..][n=l&31],
// C/D[row=(rg&3)+8*(rg>>2)+4*(l>>5)][col=l&31].

typedef __bf16 bf16x8 __attribute__((ext_vector_type(8)));
typedef __bf16 bf16x4 __attribute__((ext_vector_type(4)));
typedef float  f32x16 __attribute__((ext_vector_type(16)));

#define NT 256
#define NEG_BIG (-3.0e38f)

__device__ __forceinline__ int swz(int row, int gran) {
    return row * 64 + ((gran ^ ((row >> 1) & 7)) << 3);
}

// v_permlane32_swap_b32 a, b:  a' = {a[0:31], b[0:31]}, b' = {a[32:63], b[32:63]}
__device__ __forceinline__ void plswap(unsigned &a, unsigned &b) {
    asm("v_permlane32_swap_b32 %0, %1" : "+v"(a), "+v"(b));
}

// Cross-half (lane +-32) reduce via permlane. The earlyclobber copy forces
// b into a register distinct from a (R15 bug: a=b=x got coalesced into one
// VGPR -> in-place swap -> no reduce).
__device__ __forceinline__ float xmax32(float x) {
    float a = x, b;
    asm("v_mov_b32 %0, %1" : "=&v"(b) : "v"(a));
    asm("v_permlane32_swap_b32 %0, %1" : "+v"(a), "+v"(b));
    // a[lane] = x[lane&31], b[lane] = x[32+(lane&31)]
    return fmaxf(a, b);
}

__device__ __forceinline__ float xsum32(float x) {
    float a = x, b;
    asm("v_mov_b32 %0, %1" : "=&v"(b) : "v"(a));
    asm("v_permlane32_swap_b32 %0, %1" : "+v"(a), "+v"(b));
    return a + b;
}

// ---- baked schedule (R5/R6, verified): 24 bins/bh x exactly 9 tiles ----
__device__ const int SEG_N[24] = {3,2,2,2,2,1,2,1, 1,1,1,1,1,1,1,1, 1,1,1,1,1,1,1,1};
__device__ const int SEG_IT[24][3] = {
  {0,1,2},{2,3,0},{3,4,0},{4,5,0},{5,6,0},{6,0,0},{6,7,0},{7,0,0},
  {8,0,0},{8,0,0},{9,0,0},{9,0,0},{10,0,0},{10,0,0},{11,0,0},{11,0,0},
  {12,0,0},{12,0,0},{13,0,0},{13,0,0},{14,0,0},{14,0,0},{15,0,0},{15,0,0}};
__device__ const int SEG_J0[24][3] = {
  {0,0,0},{3,0,0},{6,0,0},{7,0,0},{6,0,0},{3,0,0},{12,0,0},{7,0,0},
  {0,0,0},{9,0,0},{0,0,0},{9,0,0},{0,0,0},{9,0,0},{0,0,0},{9,0,0},
  {0,0,0},{9,0,0},{0,0,0},{9,0,0},{0,0,0},{9,0,0},{0,0,0},{9,0,0}};
__device__ const int SEG_J1[24][3] = {
  {2,4,3},{6,6,0},{8,7,0},{10,6,0},{12,3,0},{12,0,0},{14,7,0},{16,0,0},
  {9,0,0},{18,0,0},{9,0,0},{18,0,0},{9,0,0},{18,0,0},{9,0,0},{18,0,0},
  {9,0,0},{18,0,0},{9,0,0},{18,0,0},{9,0,0},{18,0,0},{9,0,0},{18,0,0}};
__device__ const int SEG_SX[24][3] = {
  {0,0,0},{1,0,0},{1,0,0},{1,0,0},{1,0,0},{1,0,0},{2,0,0},{1,0,0},
  {0,0,0},{1,0,0},{0,0,0},{1,0,0},{0,0,0},{1,0,0},{0,0,0},{1,0,0},
  {0,0,0},{1,0,0},{0,0,0},{1,0,0},{0,0,0},{1,0,0},{0,0,0},{1,0,0}};
__device__ const int NSEG_ITEM[16] = {1,1,2,2,2,2,3,2, 2,2,2,2,2,2,2,2};

__global__ __launch_bounds__(NT, 3) void flex_r16_main(
    const float* __restrict__ Q, const float* __restrict__ K,
    const float* __restrict__ V, const float* __restrict__ SINKW,
    const int* __restrict__ SWIN, void* __restrict__ WS,
    float* __restrict__ OUT, const int H, const int S)
{
    const int t    = threadIdx.x;
    const int lane = t & 63;
    const int w    = t >> 6;
    const int c    = lane & 31;
    const int hl   = lane >> 5;
    const int W    = SWIN[0];
    const float scale = 0.125f;

    const int NBH = gridDim.x / 24;
    // XCD-pinned decode: each XCD (blk&7) serves bh in {x, 8+x, 16+x, 24+x}
    int bh, b24;
    if ((NBH & 7) == 0) {
        const int xcd  = blockIdx.x & 7;
        const int rest = blockIdx.x >> 3;
        const int G    = NBH >> 3;
        bh  = (rest % G) * 8 + xcd;
        b24 = rest / G;
    } else {
        bh  = blockIdx.x / 24;
        b24 = blockIdx.x - bh * 24;
    }
    const int h   = bh % H;
    const float sw = SINKW[h];

    __shared__ __align__(16) __bf16 k_lds[2][64 * 64];
    __shared__ __align__(16) __bf16 v_lds[2][64 * 64];

    const size_t basebh = (size_t)bh * S * 64;
    const float4* kp4 = (const float4*)(K + basebh);
    const float4* vp4 = (const float4*)(V + basebh);
    __bf16* O_ws  = (__bf16*)WS;
    float2* ml_ws = (float2*)((char*)WS + (size_t)NBH * 48 * 16384);

    const int dgi = t & 15;   // V staging: dims 4dgi..+3
    const int kgi = t >> 4;   // V staging: keys 4kgi..+3
    float4 kreg[4], vreg[4];

    const int ns = SEG_N[b24];

    // ---- prefetch + stage first tile into buffer 0 ----
    {
        const int it0 = SEG_IT[b24][0];
        const int ktA0 = (2 * it0 - 16 > 0) ? (2 * it0 - 16) : 0;
        const int kt = ktA0 + SEG_J0[b24][0];
        #pragma unroll
        for (int i = 0; i < 4; ++i) kreg[i] = kp4[kt * 1024 + i * NT + t];
        #pragma unroll
        for (int kk = 0; kk < 4; ++kk) vreg[kk] = vp4[kt * 1024 + (4 * kgi + kk) * 16 + dgi];
        #pragma unroll
        for (int i = 0; i < 4; ++i) {
            const int flat = i * NT + t;
            const int key = flat >> 4, dd = flat & 15;
            float4 f = kreg[i];
            bf16x4 b = { (__bf16)f.x, (__bf16)f.y, (__bf16)f.z, (__bf16)f.w };
            *(bf16x4*)&k_lds[0][swz(key, dd >> 1) + (dd & 1) * 4] = b;
        }
        {
            float4 a0 = vreg[0], a1 = vreg[1], a2 = vreg[2], a3 = vreg[3];
            bf16x4 w0 = { (__bf16)a0.x, (__bf16)a1.x, (__bf16)a2.x, (__bf16)a3.x };
            bf16x4 w1 = { (__bf16)a0.y, (__bf16)a1.y, (__bf16)a2.y, (__bf16)a3.y };
            bf16x4 w2 = { (__bf16)a0.z, (__bf16)a1.z, (__bf16)a2.z, (__bf16)a3.z };
            bf16x4 w3 = { (__bf16)a0.w, (__bf16)a1.w, (__bf16)a2.w, (__bf16)a3.w };
            const int gv = kgi >> 1, ov = (kgi & 1) * 4;
            *(bf16x4*)&v_lds[0][swz(4 * dgi + 0, gv) + ov] = w0;
            *(bf16x4*)&v_lds[0][swz(4 * dgi + 1, gv) + ov] = w1;
            *(bf16x4*)&v_lds[0][swz(4 * dgi + 2, gv) + ov] = w2;
            *(bf16x4*)&v_lds[0][swz(4 * dgi + 3, gv) + ov] = w3;
        }
    }

    int par = 0;

    for (int s = 0; s < ns; ++s) {
        const int item = SEG_IT[b24][s];
        const int j0   = SEG_J0[b24][s];
        const int j1   = SEG_J1[b24][s];
        const int sidx = SEG_SX[b24][s];
        const int ktA  = (2 * item - 16 > 0) ? (2 * item - 16) : 0;
        const int qw0  = item * 128 + 32 * w;
        const int qi   = qw0 + c;

        // ---- Q B-fragments (pre-scaled) ----
        bf16x8 bq[4];
        {
            const float4* qp4 = (const float4*)(Q + basebh + (size_t)qi * 64);
            #pragma unroll
            for (int ks = 0; ks < 4; ++ks) {
                float4 f0 = qp4[4 * ks + 2 * hl];
                float4 f1 = qp4[4 * ks + 2 * hl + 1];
                bq[ks][0] = (__bf16)(f0.x * scale); bq[ks][1] = (__bf16)(f0.y * scale);
                bq[ks][2] = (__bf16)(f0.z * scale); bq[ks][3] = (__bf16)(f0.w * scale);
                bq[ks][4] = (__bf16)(f1.x * scale); bq[ks][5] = (__bf16)(f1.y * scale);
                bq[ks][6] = (__bf16)(f1.z * scale); bq[ks][7] = (__bf16)(f1.w * scale);
            }
        }

        float mrun = (sidx == 0) ? sw : NEG_BIG;
        float lrun = (sidx == 0) ? 1.0f : 0.0f;
        f32x16 accO0, accO1;
        #pragma unroll
        for (int i = 0; i < 16; ++i) { accO0[i] = 0.0f; accO1[i] = 0.0f; }

        for (int j = j0; j < j1; ++j) {
            const int k0 = (ktA + j) * 64;

            __syncthreads();   // buf[par] staged & visible; prev compute done

            // ---- prefetch next tile EARLY (consumed after compute) ----
            int nkt = -1;
            if (j + 1 < j1) nkt = ktA + j + 1;
            else if (s + 1 < ns) {
                const int it2 = SEG_IT[b24][s + 1];
                const int ktA2 = (2 * it2 - 16 > 0) ? (2 * it2 - 16) : 0;
                nkt = ktA2 + SEG_J0[b24][s + 1];
            }
            if (nkt >= 0) {
                #pragma unroll
                for (int i = 0; i < 4; ++i) kreg[i] = kp4[nkt * 1024 + i * NT + t];
                #pragma unroll
                for (int kk = 0; kk < 4; ++kk) vreg[kk] = vp4[nkt * 1024 + (4 * kgi + kk) * 16 + dgi];
            }

            // ---- S^T = K · Q^T ----
            const __bf16* kb = k_lds[par];
            const __bf16* vb = v_lds[par];
            f32x16 accS0, accS1;
            #pragma unroll
            for (int i = 0; i < 16; ++i) { accS0[i] = 0.0f; accS1[i] = 0.0f; }
            __builtin_amdgcn_s_setprio(1);
            #pragma unroll
            for (int ks = 0; ks < 4; ++ks) {
                bf16x8 ka0 = *(const bf16x8*)&kb[swz(c,      2 * ks + hl)];
                bf16x8 ka1 = *(const bf16x8*)&kb[swz(32 + c, 2 * ks + hl)];
                accS0 = __builtin_amdgcn_mfma_f32_32x32x16_bf16(ka0, bq[ks], accS0, 0, 0, 0);
                accS1 = __builtin_amdgcn_mfma_f32_32x32x16_bf16(ka1, bq[ks], accS1, 0, 0, 0);
            }
            __builtin_amdgcn_s_setprio(0);

            // ---- mask (wave-uniform skip when interior) ----
            const bool interior = (k0 + 63 <= qw0) && (qw0 + 31 - k0 <= W);
            if (!interior) {
                #pragma unroll
                for (int rg = 0; rg < 16; ++rg) {
                    const int kb2 = (rg & 3) + 8 * (rg >> 2) + 4 * hl;
                    const int ki0 = k0 + kb2, ki1 = k0 + 32 + kb2;
                    if (!((ki0 <= qi) && (qi - ki0 <= W))) accS0[rg] = -1e30f;
                    if (!((ki1 <= qi) && (qi - ki1 <= W))) accS1[rg] = -1e30f;
                }
            }

            // ---- online softmax (tree-max + defer-max T13) ----
            float q4[8];
            #pragma unroll
            for (int i = 0; i < 4; ++i) {
                q4[i]   = fmaxf(fmaxf(accS0[4*i], accS0[4*i+1]),
                                fmaxf(accS0[4*i+2], accS0[4*i+3]));
                q4[4+i] = fmaxf(fmaxf(accS1[4*i], accS1[4*i+1]),
                                fmaxf(accS1[4*i+2], accS1[4*i+3]));
            }
            float mx = fmaxf(fmaxf(fmaxf(q4[0], q4[1]), fmaxf(q4[2], q4[3])),
                             fmaxf(fmaxf(q4[4], q4[5]), fmaxf(q4[6], q4[7])));
            mx = xmax32(mx);
            if (!__all(mx <= mrun + 8.0f)) {
                const float mnew  = fmaxf(mrun, mx);
                const float alpha = __expf(mrun - mnew);
                lrun *= alpha;
                #pragma unroll
                for (int i = 0; i < 16; ++i) { accO0[i] *= alpha; accO1[i] *= alpha; }
                mrun = mnew;
            }
            float ps = 0.0f;
            #pragma unroll
            for (int i = 0; i < 16; ++i) { float p = __expf(accS0[i] - mrun); accS0[i] = p; ps += p; }
            #pragma unroll
            for (int i = 0; i < 16; ++i) { float p = __expf(accS1[i] - mrun); accS1[i] = p; ps += p; }
            ps = xsum32(ps);
            lrun += ps;

            // ---- P -> B-fragments via v_permlane32_swap_b32 (VALU, no LDS) ----
            union B4U { bf16x4 v; unsigned u[2]; };
            B4U a0, b0, a1, b1, a2, b2, a3, b3;
            a0.v = bf16x4{ (__bf16)accS0[0],  (__bf16)accS0[1],  (__bf16)accS0[2],  (__bf16)accS0[3]  };
            b0.v = bf16x4{ (__bf16)accS0[4],  (__bf16)accS0[5],  (__bf16)accS0[6],  (__bf16)accS0[7]  };
            a1.v = bf16x4{ (__bf16)accS0[8],  (__bf16)accS0[9],  (__bf16)accS0[10], (__bf16)accS0[11] };
            b1.v = bf16x4{ (__bf16)accS0[12], (__bf16)accS0[13], (__bf16)accS0[14], (__bf16)accS0[15] };
            a2.v = bf16x4{ (__bf16)accS1[0],  (__bf16)accS1[1],  (__bf16)accS1[2],  (__bf16)accS1[3]  };
            b2.v = bf16x4{ (__bf16)accS1[4],  (__bf16)accS1[5],  (__bf16)accS1[6],  (__bf16)accS1[7]  };
            a3.v = bf16x4{ (__bf16)accS1[8],  (__bf16)accS1[9],  (__bf16)accS1[10], (__bf16)accS1[11] };
            b3.v = bf16x4{ (__bf16)accS1[12], (__bf16)accS1[13], (__bf16)accS1[14], (__bf16)accS1[15] };
            // after swap: a = lo = {a.row0, b.row0}, b = hi = {a.row1, b.row1}
            plswap(a0.u[0], b0.u[0]); plswap(a0.u[1], b0.u[1]);
            plswap(a1.u[0], b1.u[0]); plswap(a1.u[1], b1.u[1]);
            plswap(a2.u[0], b2.u[0]); plswap(a2.u[1], b2.u[1]);
            plswap(a3.u[0], b3.u[0]); plswap(a3.u[1], b3.u[1]);
            bf16x8 bp[4];
            #pragma unroll
            for (int e = 0; e < 4; ++e) {
                bp[0][e] = a0.v[e]; bp[0][4+e] = b0.v[e];
                bp[1][e] = a1.v[e]; bp[1][4+e] = b1.v[e];
                bp[2][e] = a2.v[e]; bp[2][4+e] = b2.v[e];
                bp[3][e] = a3.v[e]; bp[3][4+e] = b3.v[e];
            }

            // ---- O^T += V^T · P^T ----
            __builtin_amdgcn_s_setprio(1);
            #pragma unroll
            for (int ks = 0; ks < 4; ++ks) {
                bf16x8 va0 = *(const bf16x8*)&vb[swz(c,      2 * ks + hl)];
                bf16x8 va1 = *(const bf16x8*)&vb[swz(32 + c, 2 * ks + hl)];
                accO0 = __builtin_amdgcn_mfma_f32_32x32x16_bf16(va0, bp[ks], accO0, 0, 0, 0);
                accO1 = __builtin_amdgcn_mfma_f32_32x32x16_bf16(va1, bp[ks], accO1, 0, 0, 0);
            }
            __builtin_amdgcn_s_setprio(0);

            // ---- stage next tile into the other buffer (consumes prefetch) ----
            if (nkt >= 0) {
                const int np = par ^ 1;
                #pragma unroll
                for (int i = 0; i < 4; ++i) {
                    const int flat = i * NT + t;
                    const int key = flat >> 4, dd = flat & 15;
                    float4 f = kreg[i];
                    bf16x4 b = { (__bf16)f.x, (__bf16)f.y, (__bf16)f.z, (__bf16)f.w };
                    *(bf16x4*)&k_lds[np][swz(key, dd >> 1) + (dd & 1) * 4] = b;
                }
                float4 a0v = vreg[0], a1v = vreg[1], a2v = vreg[2], a3v = vreg[3];
                bf16x4 w0 = { (__bf16)a0v.x, (__bf16)a1v.x, (__bf16)a2v.x, (__bf16)a3v.x };
                bf16x4 w1 = { (__bf16)a0v.y, (__bf16)a1v.y, (__bf16)a2v.y, (__bf16)a3v.y };
                bf16x4 w2 = { (__bf16)a0v.z, (__bf16)a1v.z, (__bf16)a2v.z, (__bf16)a3v.z };
                bf16x4 w3 = { (__bf16)a0v.w, (__bf16)a1v.w, (__bf16)a2v.w, (__bf16)a3v.w };
                const int gv = kgi >> 1, ov = (kgi & 1) * 4;
                *(bf16x4*)&v_lds[np][swz(4 * dgi + 0, gv) + ov] = w0;
                *(bf16x4*)&v_lds[np][swz(4 * dgi + 1, gv) + ov] = w1;
                *(bf16x4*)&v_lds[np][swz(4 * dgi + 2, gv) + ov] = w2;
                *(bf16x4*)&v_lds[np][swz(4 * dgi + 3, gv) + ov] = w3;
            }
            par ^= 1;
        }

        if (item < 2) {
            // ---- single-segment item: write normalized output directly ----
            const float inv = 1.0f / lrun;
            float* ob = OUT + basebh + (size_t)qi * 64;
            #pragma unroll
            for (int rg = 0; rg < 4; ++rg) {
                float4 f0 = { accO0[4*rg+0]*inv, accO0[4*rg+1]*inv,
                              accO0[4*rg+2]*inv, accO0[4*rg+3]*inv };
                float4 f1 = { accO1[4*rg+0]*inv, accO1[4*rg+1]*inv,
                              accO1[4*rg+2]*inv, accO1[4*rg+3]*inv };
                *(float4*)&ob[     8 * rg + 4 * hl] = f0;
                *(float4*)&ob[32 + 8 * rg + 4 * hl] = f1;
            }
        } else {
            // ---- write partials ----
            const int slot = (bh * 16 + item) * 3 + sidx;
            const int qrel = 32 * w + c;
            if (hl == 0) ml_ws[(size_t)slot * 128 + qrel] = make_float2(mrun, lrun);
            __bf16* Os = O_ws + (size_t)slot * 8192 + (size_t)qrel * 64;
            #pragma unroll
            for (int qd = 0; qd < 4; ++qd) {
                const int d0 = 8 * qd + 4 * hl;
                bf16x4 b0 = { (__bf16)accO0[4*qd+0], (__bf16)accO0[4*qd+1],
                              (__bf16)accO0[4*qd+2], (__bf16)accO0[4*qd+3] };
                bf16x4 b1 = { (__bf16)accO1[4*qd+0], (__bf16)accO1[4*qd+1],
                              (__bf16)accO1[4*qd+2], (__bf16)accO1[4*qd+3] };
                *(bf16x4*)&Os[d0]      = b0;
                *(bf16x4*)&Os[32 + d0] = b1;
            }
        }
    }
}

__global__ __launch_bounds__(256) void flex_r16_combine(
    const void* __restrict__ WS, float* __restrict__ OUT, const int H, const int S)
{
    const int NBH  = gridDim.x / 14;
    const int bi   = blockIdx.x;
    const int bh   = bi / 14;
    const int item = 2 + (bi - bh * 14);      // items 2..15 (multi-segment)
    const int ns   = NSEG_ITEM[item];
    const int t    = threadIdx.x;
    const int q    = t >> 1;
    const int half = t & 1;

    const __bf16* O_ws = (const __bf16*)WS;
    const float2* ml_ws = (const float2*)((const char*)WS + (size_t)NBH * 48 * 16384);
    const int base = (bh * 16 + item) * 3;

    float m[3], lv[3], a[3];
    float mst = NEG_BIG;
    for (int s = 0; s < ns; ++s) {
        float2 e = ml_ws[(size_t)(base + s) * 128 + q];
        m[s] = e.x; lv[s] = e.y;
        mst = fmaxf(mst, m[s]);
    }
    float lst = 0.0f;
    for (int s = 0; s < ns; ++s) { a[s] = __expf(m[s] - mst); lst += a[s] * lv[s]; }
    const float inv = 1.0f / lst;

    float acc[32];
    #pragma unroll
    for (int i = 0; i < 32; ++i) acc[i] = 0.0f;
    for (int s = 0; s < ns; ++s) {
        const __bf16* Os = O_ws + (size_t)(base + s) * 8192 + (size_t)q * 64 + 32 * half;
        const float as = a[s];
        #pragma unroll
        for (int v8 = 0; v8 < 4; ++v8) {
            bf16x8 o = *(const bf16x8*)&Os[8 * v8];
            #pragma unroll
            for (int jj = 0; jj < 8; ++jj) acc[8 * v8 + jj] += as * (float)o[jj];
        }
    }

    float* dst = OUT + (size_t)bh * S * 64 + (size_t)(item * 128 + q) * 64 + 32 * half;
    #pragma unroll
    for (int v4 = 0; v4 < 8; ++v4) {
        float4 f = { acc[4*v4+0] * inv, acc[4*v4+1] * inv,
                     acc[4*v4+2] * inv, acc[4*v4+3] * inv };
        *(float4*)&dst[4 * v4] = f;
    }
}

extern "C" void kernel_launch(void* const* d_in, const int* in_sizes, int n_in,
                              void* d_out, int out_size, void* d_ws, size_t ws_size,
                              hipStream_t stream) {
    const float* q     = (const float*)d_in[0];
    const float* k     = (const float*)d_in[1];
    const float* v     = (const float*)d_in[2];
    const float* sinkw = (const float*)d_in[3];
    const int*   swin  = (const int*)d_in[4];
    float* out = (float*)d_out;

    const int H = in_sizes[3];                   // 16
    const int S = 2048;
    const int B = in_sizes[0] / (H * S * 64);    // 2
    const int NBH = B * H;                       // 32

    flex_r16_main<<<dim3(NBH * 24), NT, 0, stream>>>(q, k, v, sinkw, swin, d_ws, out, H, S);
    flex_r16_combine<<<dim3(NBH * 14), 256, 0, stream>>>(d_ws, out, H, S);
}